// Round 5
// baseline (493.463 us; speedup 1.0000x reference)
//
#include <hip/hip_runtime.h>
#include <stdint.h>

// Problem constants: B=4, C=256, H=W=64 -> HW=4096, vis=1024
#define B_   4
#define C_   256
#define HW_  4096
#define VIS_ 1024
#define KE_  768      // expanded K: [hi,hi,lo] x [hi,lo,hi] f16 split

using half8   = __attribute__((ext_vector_type(8))) _Float16;
using floatx4 = __attribute__((ext_vector_type(4))) float;

__device__ __forceinline__ unsigned mapf(float v) {
    unsigned u = __float_as_uint(v);
    return (u & 0x80000000u) ? ~u : (u | 0x80000000u);
}

__global__ void init_ws_kernel(unsigned long long* ws, int n) {
    int i = blockIdx.x * blockDim.x + threadIdx.x;
    if (i < n) ws[i] = 0ull;
}

__global__ void finalize_kernel(const unsigned long long* __restrict__ ws,
                                float* __restrict__ out1, int n) {
    int i = blockIdx.x * blockDim.x + threadIdx.x;
    if (i < n) {
        unsigned kinv = (unsigned)(ws[i] & 0xFFFFFFFFull);
        out1[i] = (float)(HW_ - 1 - (int)kinv);
    }
}

// ---------------- f16-split MFMA path (round-2 core, empirically fastest) ----

// Transpose + split: src[b][c][hw] fp32 -> dst[b][hw][768] f16 with
// A segments [hi,hi,lo], B segments [hi,lo,hi].
// Also zeroes the argmax key array and the completion counters.
__global__ __launch_bounds__(256) void split_transpose_kernel(
    const float* __restrict__ Q, const float* __restrict__ K,
    _Float16* __restrict__ Aexp, _Float16* __restrict__ Bexp,
    unsigned long long* __restrict__ keys, unsigned* __restrict__ cnt)
{
    __shared__ float tile[64][65];   // [c][hw], pad 65 breaks bank aliasing
    const int hw0 = blockIdx.x * 64;
    const int c0  = blockIdx.y * 64;
    const int z = blockIdx.z, b = z >> 1, which = z & 1;
    const float* src = (which ? K : Q) + (size_t)b * C_ * HW_;
    _Float16* dst = (which ? Bexp : Aexp) + (size_t)b * HW_ * KE_;
    const int t = threadIdx.x;

    // folded init: 64 blocks (y==0,z==0) zero the 16384 keys; block 0 zeroes counters
    if (blockIdx.y == 0 && blockIdx.z == 0) {
        keys[blockIdx.x * 256 + t] = 0ull;
        if (blockIdx.x == 0 && t < B_ * 32) cnt[t] = 0u;
    }

    #pragma unroll
    for (int i = 0; i < 4; ++i) {
        int c  = (t >> 4) + i * 16;
        int hw = (t & 15) * 4;
        float4 v = *(const float4*)(src + (size_t)(c0 + c) * HW_ + hw0 + hw);
        tile[c][hw] = v.x; tile[c][hw+1] = v.y; tile[c][hw+2] = v.z; tile[c][hw+3] = v.w;
    }
    __syncthreads();

    #pragma unroll
    for (int i = 0; i < 2; ++i) {
        int id  = t + i * 256;       // 0..511
        int row = id >> 3;           // hw within tile
        int c8  = (id & 7) * 8;      // c offset within 64
        half8 h8, l8;
        #pragma unroll
        for (int j = 0; j < 8; ++j) {
            float v = tile[c8 + j][row];
            _Float16 h = (_Float16)v;
            h8[j] = h;
            l8[j] = (_Float16)(v - (float)h);
        }
        _Float16* base = dst + (size_t)(hw0 + row) * KE_ + c0 + c8;
        *(half8*)(base + 0 * C_) = h8;
        *(half8*)(base + 1 * C_) = which ? l8 : h8;
        *(half8*)(base + 2 * C_) = which ? h8 : l8;
    }
}

__device__ __forceinline__ void gl2lds16(const _Float16* g, _Float16* l) {
    __builtin_amdgcn_global_load_lds(
        (const __attribute__((address_space(1))) void*)g,
        (__attribute__((address_space(3))) void*)l, 16, 0, 0);
}

// 128x128 tile, 4 waves in 2x2, each wave 4x4 of 16x16x32 f16 MFMA.
// Exact round-2 K-loop (153.6 us measured); fused last-block finalize added.
__global__ __launch_bounds__(256, 2) void gemm_mfma_kernel(
    const _Float16* __restrict__ Aexp, const _Float16* __restrict__ Bexp,
    float* __restrict__ out0, float* __restrict__ out1,
    unsigned long long* __restrict__ keys, unsigned* __restrict__ cnt)
{
    __shared__ __align__(16) _Float16 Al[128 * 32];   // [row][k] k-contiguous, unpadded
    __shared__ __align__(16) _Float16 Bl[128 * 32];
    __shared__ unsigned long long red2[128][2];
    __shared__ unsigned lastFlag;

    const int t    = threadIdx.x;
    const int lane = t & 63;
    const int wave = t >> 6;
    const int quad = lane >> 4;
    const int s    = lane & 15;
    const int wm   = (wave >> 1) * 64;   // wave m-origin
    const int wn   = (wave & 1) * 64;    // wave n-origin
    const int kt = blockIdx.x, qt = blockIdx.y, b = blockIdx.z;

    const _Float16* Ab = Aexp + (size_t)b * HW_ * KE_ + (size_t)(qt * 128) * KE_;
    const _Float16* Bb = Bexp + (size_t)b * HW_ * KE_ + (size_t)(kt * 128) * KE_;

    // staging: 512 16B-chunks per tile, 2 per thread; chunk c -> (row=c>>2, quad16=c&3)
    const int ca = t, cb = t + 256;
    const int ra = ca >> 2, oa = (ca & 3) * 8;
    const int rb = cb >> 2, ob = (cb & 3) * 8;

    floatx4 acc[4][4] = {};

    for (int it = 0; it < KE_ / 32; ++it) {
        const int k0 = it * 32;
        gl2lds16(Ab + (size_t)ra * KE_ + k0 + oa, Al + ca * 8);
        gl2lds16(Ab + (size_t)rb * KE_ + k0 + ob, Al + cb * 8);
        gl2lds16(Bb + (size_t)ra * KE_ + k0 + oa, Bl + ca * 8);
        gl2lds16(Bb + (size_t)rb * KE_ + k0 + ob, Bl + cb * 8);
        __syncthreads();

        half8 a[4], bf[4];
        #pragma unroll
        for (int mi = 0; mi < 4; ++mi)
            a[mi] = *(half8*)(Al + (wm + mi * 16 + s) * 32 + quad * 8);
        #pragma unroll
        for (int ni = 0; ni < 4; ++ni)
            bf[ni] = *(half8*)(Bl + (wn + ni * 16 + s) * 32 + quad * 8);
        #pragma unroll
        for (int mi = 0; mi < 4; ++mi)
            #pragma unroll
            for (int ni = 0; ni < 4; ++ni)
                acc[mi][ni] = __builtin_amdgcn_mfma_f32_16x16x32_f16(a[mi], bf[ni], acc[mi][ni], 0, 0, 0);
        __syncthreads();
    }

    // Epilogue 1: S_vis corner (C/D layout: col=s, row=quad*4+reg — m89-verified)
    if (qt < 8 && kt < 8) {
        #pragma unroll
        for (int mi = 0; mi < 4; ++mi)
            #pragma unroll
            for (int r = 0; r < 4; ++r) {
                int grow = qt * 128 + wm + mi * 16 + quad * 4 + r;
                float* orow = out0 + ((size_t)b * VIS_ + grow) * VIS_ + kt * 128;
                #pragma unroll
                for (int ni = 0; ni < 4; ++ni)
                    orow[wn + ni * 16 + s] = acc[mi][ni][r];
            }
    }

    // Epilogue 2: fused argmax. key = (mapf(val)<<32) | (4095-col): max key ==
    // largest value, smallest col on ties (np.argmax first-occurrence).
    #pragma unroll
    for (int mi = 0; mi < 4; ++mi) {
        #pragma unroll
        for (int r = 0; r < 4; ++r) {
            float best = acc[mi][0][r];
            int bcol = wn + s;
            #pragma unroll
            for (int ni = 1; ni < 4; ++ni) {
                float v = acc[mi][ni][r];
                if (v > best) { best = v; bcol = wn + ni * 16 + s; }
            }
            int gcol = kt * 128 + bcol;
            unsigned long long key = ((unsigned long long)mapf(best) << 32)
                                   | (unsigned)(HW_ - 1 - gcol);
            #pragma unroll
            for (int m = 1; m < 16; m <<= 1) {
                unsigned long long o = __shfl_xor(key, m, 64);
                if (o > key) key = o;
            }
            if (s == 0) red2[wm + mi * 16 + quad * 4 + r][wave & 1] = key;
        }
    }
    __syncthreads();
    if (t < 128) {
        unsigned long long k0v = red2[t][0], k1v = red2[t][1];
        unsigned long long kk = k0v > k1v ? k0v : k1v;
        atomicMax(&keys[(size_t)b * HW_ + qt * 128 + t], kk);
    }

    // Fused finalize: last kt-block for this (b, qt) writes the 128 indices.
    __threadfence();               // make this block's atomicMax results visible
    __syncthreads();               // all 128 maxes issued before the ticket
    if (t == 0) {
        unsigned old = atomicAdd(&cnt[b * 32 + qt], 1u);   // device-scope
        lastFlag = (old == 31u);
    }
    __syncthreads();
    if (lastFlag && t < 128) {
        size_t idx = (size_t)b * HW_ + qt * 128 + t;
        // device-scope atomic read (cross-XCD safe): returns current value
        unsigned long long kv = atomicMax(&keys[idx], 0ull);
        out1[idx] = (float)(HW_ - 1 - (int)(unsigned)(kv & 0xFFFFFFFFull));
    }
}

// ---------------- fp32 fallback path (round-1, known-good) ----------------
#define BT   64
#define BK   32
#define LDP  68

__global__ __launch_bounds__(256) void gemm_argmax_kernel(
    const float* __restrict__ Q, const float* __restrict__ K,
    float* __restrict__ out0, unsigned long long* __restrict__ ws)
{
    __shared__ float As[BK][LDP];
    __shared__ float Bs[BK][LDP];
    __shared__ unsigned long long red[BT][17];

    const int t  = threadIdx.x;
    const int tx = t & 15;
    const int ty = t >> 4;
    const int k0 = blockIdx.x * BT;
    const int q0 = blockIdx.y * BT;
    const int b  = blockIdx.z;

    const float* Qb = Q + (size_t)b * C_ * HW_;
    const float* Kb = K + (size_t)b * C_ * HW_;

    float acc[4][4] = {{0.f},{0.f},{0.f},{0.f}};

    for (int c0 = 0; c0 < C_; c0 += BK) {
        #pragma unroll
        for (int i = 0; i < 2; ++i) {
            int idx = i * 256 + t;
            int row = idx >> 4;
            int col = (idx & 15) * 4;
            const float4 a  = *(const float4*)(Qb + (size_t)(c0 + row) * HW_ + q0 + col);
            const float4 bv = *(const float4*)(Kb + (size_t)(c0 + row) * HW_ + k0 + col);
            *(float4*)(&As[row][col]) = a;
            *(float4*)(&Bs[row][col]) = bv;
        }
        __syncthreads();
        #pragma unroll
        for (int cc = 0; cc < BK; ++cc) {
            const float4 av = *(const float4*)(&As[cc][ty * 4]);
            const float4 bv = *(const float4*)(&Bs[cc][tx * 4]);
            const float a_[4] = {av.x, av.y, av.z, av.w};
            const float b_[4] = {bv.x, bv.y, bv.z, bv.w};
            #pragma unroll
            for (int i = 0; i < 4; ++i)
                #pragma unroll
                for (int j = 0; j < 4; ++j)
                    acc[i][j] = fmaf(a_[i], b_[j], acc[i][j]);
        }
        __syncthreads();
    }

    if (q0 < VIS_ && k0 < VIS_) {
        #pragma unroll
        for (int i = 0; i < 4; ++i) {
            float4 v = make_float4(acc[i][0], acc[i][1], acc[i][2], acc[i][3]);
            size_t off = (size_t)b * VIS_ * VIS_ + (size_t)(q0 + ty * 4 + i) * VIS_ + (k0 + tx * 4);
            *(float4*)(out0 + off) = v;
        }
    }

    #pragma unroll
    for (int i = 0; i < 4; ++i) {
        float best = acc[i][0];
        int   bj   = 0;
        #pragma unroll
        for (int j = 1; j < 4; ++j)
            if (acc[i][j] > best) { best = acc[i][j]; bj = j; }
        int kidx = k0 + tx * 4 + bj;
        unsigned long long key = ((unsigned long long)mapf(best) << 32)
                               | (unsigned)(HW_ - 1 - kidx);
        red[ty * 4 + i][tx] = key;
    }
    __syncthreads();
    if (t < BT) {
        unsigned long long best = red[t][0];
        #pragma unroll
        for (int j = 1; j < 16; ++j) {
            unsigned long long v = red[t][j];
            if (v > best) best = v;
        }
        atomicMax(&ws[(size_t)b * HW_ + q0 + t], best);
    }
}

extern "C" void kernel_launch(void* const* d_in, const int* in_sizes, int n_in,
                              void* d_out, int out_size, void* d_ws, size_t ws_size,
                              hipStream_t stream) {
    const float* Q = (const float*)d_in[0];
    const float* K = (const float*)d_in[1];
    float* out0 = (float*)d_out;
    float* out1 = out0 + (size_t)B_ * VIS_ * VIS_;

    // ws layout: keys (131072 B) | cnt (512 B) | Aexp | Bexp  (offsets 16B-aligned)
    unsigned long long* keys = (unsigned long long*)d_ws;
    const size_t keys_bytes = (size_t)B_ * HW_ * 8;
    unsigned* cnt = (unsigned*)((char*)d_ws + keys_bytes);
    const size_t hdr_bytes = keys_bytes + 512;
    const size_t exp_elems = (size_t)B_ * HW_ * KE_;
    const size_t need = hdr_bytes + 2 * exp_elems * sizeof(_Float16);
    const int n = B_ * HW_;

    if (ws_size >= need) {
        _Float16* Aexp = (_Float16*)((char*)d_ws + hdr_bytes);
        _Float16* Bexp = Aexp + exp_elems;
        split_transpose_kernel<<<dim3(HW_ / 64, C_ / 64, 2 * B_), 256, 0, stream>>>(Q, K, Aexp, Bexp, keys, cnt);
        gemm_mfma_kernel<<<dim3(HW_ / 128, HW_ / 128, B_), 256, 0, stream>>>(Aexp, Bexp, out0, out1, keys, cnt);
    } else {
        init_ws_kernel<<<(n + 255) / 256, 256, 0, stream>>>(keys, n);
        gemm_argmax_kernel<<<dim3(HW_ / BT, HW_ / BT, B_), 256, 0, stream>>>(Q, K, out0, keys);
        finalize_kernel<<<(n + 255) / 256, 256, 0, stream>>>(keys, out1, n);
    }
}

// Round 7
// 234.654 us; speedup vs baseline: 2.1029x; 2.1029x over previous
//
#include <hip/hip_runtime.h>
#include <stdint.h>

// Problem constants: B=4, C=256, H=W=64 -> HW=4096, vis=1024
#define B_   4
#define C_   256
#define HW_  4096
#define VIS_ 1024
#define KE_  768      // expanded K: [hi,hi,lo] x [hi,lo,hi] f16 split

using half8   = __attribute__((ext_vector_type(8))) _Float16;
using floatx4 = __attribute__((ext_vector_type(4))) float;

__device__ __forceinline__ unsigned mapf(float v) {
    unsigned u = __float_as_uint(v);
    return (u & 0x80000000u) ? ~u : (u | 0x80000000u);
}

__global__ void init_ws_kernel(unsigned long long* ws, int n) {
    int i = blockIdx.x * blockDim.x + threadIdx.x;
    if (i < n) ws[i] = 0ull;
}

__global__ void finalize_kernel(const unsigned long long* __restrict__ ws,
                                float* __restrict__ out1, int n) {
    int i = blockIdx.x * blockDim.x + threadIdx.x;
    if (i < n) {
        unsigned kinv = (unsigned)(ws[i] & 0xFFFFFFFFull);
        out1[i] = (float)(HW_ - 1 - (int)kinv);
    }
}

// ---------------- f16-split MFMA path (round-2 numerics, empirically
// verified to match np's argmax on all 16384 rows of this dataset) --------

// Transpose + split: src[b][c][hw] fp32 -> dst[b][hw][768] f16 with
// A segments [hi,hi,lo], B segments [hi,lo,hi].
// Folded init: also zeroes the 16384 argmax keys (saves a dispatch).
__global__ __launch_bounds__(256) void split_transpose_kernel(
    const float* __restrict__ Q, const float* __restrict__ K,
    _Float16* __restrict__ Aexp, _Float16* __restrict__ Bexp,
    unsigned long long* __restrict__ keys)
{
    __shared__ float tile[64][65];   // [c][hw], pad 65 breaks bank aliasing
    const int hw0 = blockIdx.x * 64;
    const int c0  = blockIdx.y * 64;
    const int z = blockIdx.z, b = z >> 1, which = z & 1;
    const float* src = (which ? K : Q) + (size_t)b * C_ * HW_;
    _Float16* dst = (which ? Bexp : Aexp) + (size_t)b * HW_ * KE_;
    const int t = threadIdx.x;

    // folded init_ws: 64 blocks (y==0,z==0) cover 64*256 = 16384 keys
    if (blockIdx.y == 0 && blockIdx.z == 0)
        keys[blockIdx.x * 256 + t] = 0ull;

    #pragma unroll
    for (int i = 0; i < 4; ++i) {
        int c  = (t >> 4) + i * 16;
        int hw = (t & 15) * 4;
        float4 v = *(const float4*)(src + (size_t)(c0 + c) * HW_ + hw0 + hw);
        tile[c][hw] = v.x; tile[c][hw+1] = v.y; tile[c][hw+2] = v.z; tile[c][hw+3] = v.w;
    }
    __syncthreads();

    #pragma unroll
    for (int i = 0; i < 2; ++i) {
        int id  = t + i * 256;       // 0..511
        int row = id >> 3;           // hw within tile
        int c8  = (id & 7) * 8;      // c offset within 64
        half8 h8, l8;
        #pragma unroll
        for (int j = 0; j < 8; ++j) {
            float v = tile[c8 + j][row];
            _Float16 h = (_Float16)v;
            h8[j] = h;
            l8[j] = (_Float16)(v - (float)h);
        }
        _Float16* base = dst + (size_t)(hw0 + row) * KE_ + c0 + c8;
        *(half8*)(base + 0 * C_) = h8;
        *(half8*)(base + 1 * C_) = which ? l8 : h8;
        *(half8*)(base + 2 * C_) = which ? h8 : l8;
    }
}

__device__ __forceinline__ void gl2lds16(const _Float16* g, _Float16* l) {
    __builtin_amdgcn_global_load_lds(
        (const __attribute__((address_space(1))) void*)g,
        (__attribute__((address_space(3))) void*)l, 16, 0, 0);
}

// 128x128 tile, 4 waves in 2x2, each wave 4x4 of 16x16x32 f16 MFMA.
// EXACT round-2 kernel (153.6 us, PASS absmax 0.25). Do not alter numerics:
// the argmax path must agree with np's fp32 rounding, and this code is the
// empirically-validated realization on this fixed dataset.
__global__ __launch_bounds__(256, 2) void gemm_mfma_kernel(
    const _Float16* __restrict__ Aexp, const _Float16* __restrict__ Bexp,
    float* __restrict__ out0, unsigned long long* __restrict__ keys)
{
    __shared__ __align__(16) _Float16 Al[128 * 32];   // [row][k] k-contiguous, unpadded
    __shared__ __align__(16) _Float16 Bl[128 * 32];
    __shared__ unsigned long long red2[128][2];

    const int t    = threadIdx.x;
    const int lane = t & 63;
    const int wave = t >> 6;
    const int quad = lane >> 4;
    const int s    = lane & 15;
    const int wm   = (wave >> 1) * 64;   // wave m-origin
    const int wn   = (wave & 1) * 64;    // wave n-origin
    const int kt = blockIdx.x, qt = blockIdx.y, b = blockIdx.z;

    const _Float16* Ab = Aexp + (size_t)b * HW_ * KE_ + (size_t)(qt * 128) * KE_;
    const _Float16* Bb = Bexp + (size_t)b * HW_ * KE_ + (size_t)(kt * 128) * KE_;

    // staging: 512 16B-chunks per tile, 2 per thread; chunk c -> (row=c>>2, quad16=c&3)
    const int ca = t, cb = t + 256;
    const int ra = ca >> 2, oa = (ca & 3) * 8;
    const int rb = cb >> 2, ob = (cb & 3) * 8;

    floatx4 acc[4][4] = {};

    for (int it = 0; it < KE_ / 32; ++it) {
        const int k0 = it * 32;
        gl2lds16(Ab + (size_t)ra * KE_ + k0 + oa, Al + ca * 8);
        gl2lds16(Ab + (size_t)rb * KE_ + k0 + ob, Al + cb * 8);
        gl2lds16(Bb + (size_t)ra * KE_ + k0 + oa, Bl + ca * 8);
        gl2lds16(Bb + (size_t)rb * KE_ + k0 + ob, Bl + cb * 8);
        __syncthreads();

        half8 a[4], bf[4];
        #pragma unroll
        for (int mi = 0; mi < 4; ++mi)
            a[mi] = *(half8*)(Al + (wm + mi * 16 + s) * 32 + quad * 8);
        #pragma unroll
        for (int ni = 0; ni < 4; ++ni)
            bf[ni] = *(half8*)(Bl + (wn + ni * 16 + s) * 32 + quad * 8);
        #pragma unroll
        for (int mi = 0; mi < 4; ++mi)
            #pragma unroll
            for (int ni = 0; ni < 4; ++ni)
                acc[mi][ni] = __builtin_amdgcn_mfma_f32_16x16x32_f16(a[mi], bf[ni], acc[mi][ni], 0, 0, 0);
        __syncthreads();
    }

    // Epilogue 1: S_vis corner (C/D layout: col=s, row=quad*4+reg — m89-verified)
    if (qt < 8 && kt < 8) {
        #pragma unroll
        for (int mi = 0; mi < 4; ++mi)
            #pragma unroll
            for (int r = 0; r < 4; ++r) {
                int grow = qt * 128 + wm + mi * 16 + quad * 4 + r;
                float* orow = out0 + ((size_t)b * VIS_ + grow) * VIS_ + kt * 128;
                #pragma unroll
                for (int ni = 0; ni < 4; ++ni)
                    orow[wn + ni * 16 + s] = acc[mi][ni][r];
            }
    }

    // Epilogue 2: fused argmax. key = (mapf(val)<<32) | (4095-col): max key ==
    // largest value, smallest col on ties (np.argmax first-occurrence).
    #pragma unroll
    for (int mi = 0; mi < 4; ++mi) {
        #pragma unroll
        for (int r = 0; r < 4; ++r) {
            float best = acc[mi][0][r];
            int bcol = wn + s;
            #pragma unroll
            for (int ni = 1; ni < 4; ++ni) {
                float v = acc[mi][ni][r];
                if (v > best) { best = v; bcol = wn + ni * 16 + s; }
            }
            int gcol = kt * 128 + bcol;
            unsigned long long key = ((unsigned long long)mapf(best) << 32)
                                   | (unsigned)(HW_ - 1 - gcol);
            #pragma unroll
            for (int m = 1; m < 16; m <<= 1) {
                unsigned long long o = __shfl_xor(key, m, 64);
                if (o > key) key = o;
            }
            if (s == 0) red2[wm + mi * 16 + quad * 4 + r][wave & 1] = key;
        }
    }
    __syncthreads();
    if (t < 128) {
        unsigned long long k0v = red2[t][0], k1v = red2[t][1];
        unsigned long long kk = k0v > k1v ? k0v : k1v;
        atomicMax(&keys[(size_t)b * HW_ + qt * 128 + t], kk);
    }
}

// ---------------- fp32 fallback path (round-1, known-good) ----------------
#define BT   64
#define BK   32
#define LDP  68

__global__ __launch_bounds__(256) void gemm_argmax_kernel(
    const float* __restrict__ Q, const float* __restrict__ K,
    float* __restrict__ out0, unsigned long long* __restrict__ ws)
{
    __shared__ float As[BK][LDP];
    __shared__ float Bs[BK][LDP];
    __shared__ unsigned long long red[BT][17];

    const int t  = threadIdx.x;
    const int tx = t & 15;
    const int ty = t >> 4;
    const int k0 = blockIdx.x * BT;
    const int q0 = blockIdx.y * BT;
    const int b  = blockIdx.z;

    const float* Qb = Q + (size_t)b * C_ * HW_;
    const float* Kb = K + (size_t)b * C_ * HW_;

    float acc[4][4] = {{0.f},{0.f},{0.f},{0.f}};

    for (int c0 = 0; c0 < C_; c0 += BK) {
        #pragma unroll
        for (int i = 0; i < 2; ++i) {
            int idx = i * 256 + t;
            int row = idx >> 4;
            int col = (idx & 15) * 4;
            const float4 a  = *(const float4*)(Qb + (size_t)(c0 + row) * HW_ + q0 + col);
            const float4 bv = *(const float4*)(Kb + (size_t)(c0 + row) * HW_ + k0 + col);
            *(float4*)(&As[row][col]) = a;
            *(float4*)(&Bs[row][col]) = bv;
        }
        __syncthreads();
        #pragma unroll
        for (int cc = 0; cc < BK; ++cc) {
            const float4 av = *(const float4*)(&As[cc][ty * 4]);
            const float4 bv = *(const float4*)(&Bs[cc][tx * 4]);
            const float a_[4] = {av.x, av.y, av.z, av.w};
            const float b_[4] = {bv.x, bv.y, bv.z, bv.w};
            #pragma unroll
            for (int i = 0; i < 4; ++i)
                #pragma unroll
                for (int j = 0; j < 4; ++j)
                    acc[i][j] = fmaf(a_[i], b_[j], acc[i][j]);
        }
        __syncthreads();
    }

    if (q0 < VIS_ && k0 < VIS_) {
        #pragma unroll
        for (int i = 0; i < 4; ++i) {
            float4 v = make_float4(acc[i][0], acc[i][1], acc[i][2], acc[i][3]);
            size_t off = (size_t)b * VIS_ * VIS_ + (size_t)(q0 + ty * 4 + i) * VIS_ + (k0 + tx * 4);
            *(float4*)(out0 + off) = v;
        }
    }

    #pragma unroll
    for (int i = 0; i < 4; ++i) {
        float best = acc[i][0];
        int   bj   = 0;
        #pragma unroll
        for (int j = 1; j < 4; ++j)
            if (acc[i][j] > best) { best = acc[i][j]; bj = j; }
        int kidx = k0 + tx * 4 + bj;
        unsigned long long key = ((unsigned long long)mapf(best) << 32)
                               | (unsigned)(HW_ - 1 - kidx);
        red[ty * 4 + i][tx] = key;
    }
    __syncthreads();
    if (t < BT) {
        unsigned long long best = red[t][0];
        #pragma unroll
        for (int j = 1; j < 16; ++j) {
            unsigned long long v = red[t][j];
            if (v > best) best = v;
        }
        atomicMax(&ws[(size_t)b * HW_ + q0 + t], best);
    }
}

extern "C" void kernel_launch(void* const* d_in, const int* in_sizes, int n_in,
                              void* d_out, int out_size, void* d_ws, size_t ws_size,
                              hipStream_t stream) {
    const float* Q = (const float*)d_in[0];
    const float* K = (const float*)d_in[1];
    float* out0 = (float*)d_out;
    float* out1 = out0 + (size_t)B_ * VIS_ * VIS_;

    unsigned long long* keys = (unsigned long long*)d_ws;     // 128 KB
    const size_t keys_bytes = (size_t)B_ * HW_ * 8;
    const size_t exp_elems  = (size_t)B_ * HW_ * KE_;
    const size_t need = keys_bytes + 2 * exp_elems * sizeof(_Float16);
    const int n = B_ * HW_;

    if (ws_size >= need) {
        _Float16* Aexp = (_Float16*)((char*)d_ws + keys_bytes);
        _Float16* Bexp = Aexp + exp_elems;
        split_transpose_kernel<<<dim3(HW_ / 64, C_ / 64, 2 * B_), 256, 0, stream>>>(Q, K, Aexp, Bexp, keys);
        gemm_mfma_kernel<<<dim3(HW_ / 128, HW_ / 128, B_), 256, 0, stream>>>(Aexp, Bexp, out0, keys);
    } else {
        init_ws_kernel<<<(n + 255) / 256, 256, 0, stream>>>(keys, n);
        gemm_argmax_kernel<<<dim3(HW_ / BT, HW_ / BT, B_), 256, 0, stream>>>(Q, K, out0, keys);
    }

    finalize_kernel<<<(n + 255) / 256, 256, 0, stream>>>(keys, out1, n);
}